// Round 16
// baseline (103.813 us; speedup 1.0000x reference)
//
#include <hip/hip_runtime.h>
#include <hip/hip_bf16.h>
#include <math.h>

// Problem constants
static constexpr int kB = 8;
static constexpr int kH = 8;
static constexpr int kL = 512;
static constexpr int kD = 512;
static constexpr int kDH = 64;     // D/H
static constexpr int kBH = 64;     // B*H
static constexpr int kROWS = kBH * kL;  // 32768

typedef short bf16x8 __attribute__((ext_vector_type(8)));
typedef float f32x4 __attribute__((ext_vector_type(4)));

// RNE float->bf16 (finite inputs only)
__device__ __forceinline__ ushort f2bf(float f) {
    unsigned u = __float_as_uint(f);
    unsigned r = u + 0x7fffu + ((u >> 16) & 1u);
    return (ushort)(r >> 16);
}
__device__ __forceinline__ float bf2f(ushort h) {
    return __uint_as_float((unsigned)h << 16);
}
// order-isomorphic float<->uint maps (finite, no NaN; -0.0 < +0.0 in key order)
__device__ __forceinline__ unsigned mapf(float f) {
    unsigned u = __float_as_uint(f);
    return (u & 0x80000000u) ? ~u : (u | 0x80000000u);
}
__device__ __forceinline__ float unmapf(unsigned u) {
    return (u & 0x80000000u) ? __uint_as_float(u ^ 0x80000000u)
                             : __uint_as_float(~u);
}

// gelu with A&S 7.1.26 erf (max abs err ~1.5e-7, monotone-preserving)
__device__ __forceinline__ float gelu_fast(float v) {
    float z = v * 0.70710678118654752440f;
    float az = fabsf(z);
    float t = 1.0f / (1.0f + 0.3275911f * az);
    float ex = __expf(-az * az);
    float poly = t * (0.254829592f + t * (-0.284496736f + t * (1.421413741f +
                 t * (-1.453152027f + t * 1.061405429f))));
    float erfv = 1.0f - poly * ex;
    erfv = (z < 0.0f) ? -erfv : erfv;
    return 0.5f * v * (1.0f + erfv);
}

// ---------------------------------------------------------------------------
// K1 (merged): blocks 0..511: q/k projection (split-bf16 MFMA, hi/lo out);
// blocks 512..1023: xp = x @ Wp^T + bp -> transposed bf16 xpbT (MFMA).
// Both branches only read x + weights (independent). LDS aliased (18.4 KB).
// ---------------------------------------------------------------------------
__global__ __launch_bounds__(256) void k_qk_xp(const float* __restrict__ x,
        const float* __restrict__ W1, const float* __restrict__ b1,
        const float* __restrict__ W2, const float* __restrict__ b2,
        const float* __restrict__ Wp, const float* __restrict__ bp,
        ushort* __restrict__ qh, ushort* __restrict__ ql,
        ushort* __restrict__ kh, ushort* __restrict__ kl,
        ushort* __restrict__ xpbT) {
    __shared__ __align__(16) char smem[2 * 64 * 72 * 2];
    int tid = threadIdx.x;
    int blk = blockIdx.x;
    int lane = tid & 63, wave = tid >> 6;
    if (blk < 512) {
        // ------- qk branch (split-bf16 MFMA; q||k, 4 waves: wq x wn) -------
        int b = blk >> 6, h = (blk >> 3) & 7, lt = blk & 7;
        ushort (*xhi)[72] = (ushort(*)[72])smem;
        ushort (*xlo)[72] = (ushort(*)[72])(smem + 64 * 72 * 2);
        {
            int r = tid >> 2, s = tid & 3;
            const float* src = x + (size_t)(b * kL + lt * 64 + r) * kD + h * kDH + s * 16;
            union { ushort u[16]; int4 v[2]; } ph, pl;
            #pragma unroll
            for (int c4 = 0; c4 < 4; ++c4) {
                float4 f = *(const float4*)(src + c4 * 4);
                float fv[4] = {f.x, f.y, f.z, f.w};
                #pragma unroll
                for (int t = 0; t < 4; ++t) {
                    ushort hh = f2bf(fv[t]);
                    ph.u[c4 * 4 + t] = hh;
                    pl.u[c4 * 4 + t] = f2bf(fv[t] - bf2f(hh));
                }
            }
            *(int4*)&xhi[r][s * 16] = ph.v[0];
            *(int4*)&xhi[r][s * 16 + 8] = ph.v[1];
            *(int4*)&xlo[r][s * 16] = pl.v[0];
            *(int4*)&xlo[r][s * 16 + 8] = pl.v[1];
        }
        int wq = wave >> 1, wn = wave & 1;
        const float* Wm = wq ? W2 : W1;
        const float* bias = wq ? b2 : b1;
        int coff = (lane >> 4) * 8;
        // B fragments from global (L2-resident), on-the-fly hi/lo split
        bf16x8 bh8[2][2], bl8[2][2];   // [fn][kk]
        #pragma unroll
        for (int fn = 0; fn < 2; ++fn) {
            int browg = wn * 32 + fn * 16 + (lane & 15);
            #pragma unroll
            for (int kk = 0; kk < 2; ++kk) {
                const float* wsrc = Wm + browg * 64 + kk * 32 + coff;
                float4 f0 = *(const float4*)(wsrc);
                float4 f1 = *(const float4*)(wsrc + 4);
                float fv[8] = {f0.x, f0.y, f0.z, f0.w, f1.x, f1.y, f1.z, f1.w};
                union { ushort u[8]; bf16x8 v; } uh, ul;
                #pragma unroll
                for (int t = 0; t < 8; ++t) {
                    ushort hh = f2bf(fv[t]);
                    uh.u[t] = hh;
                    ul.u[t] = f2bf(fv[t] - bf2f(hh));
                }
                bh8[fn][kk] = uh.v;
                bl8[fn][kk] = ul.v;
            }
        }
        __syncthreads();
        f32x4 acc[4][2] = {};
        #pragma unroll
        for (int kk = 0; kk < 2; ++kk)
            #pragma unroll
            for (int fm = 0; fm < 4; ++fm) {
                bf16x8 ah8 = *(const bf16x8*)&xhi[fm * 16 + (lane & 15)][kk * 32 + coff];
                bf16x8 al8 = *(const bf16x8*)&xlo[fm * 16 + (lane & 15)][kk * 32 + coff];
                #pragma unroll
                for (int fn = 0; fn < 2; ++fn) {
                    acc[fm][fn] = __builtin_amdgcn_mfma_f32_16x16x32_bf16(
                        ah8, bh8[fn][kk], acc[fm][fn], 0, 0, 0);
                    acc[fm][fn] = __builtin_amdgcn_mfma_f32_16x16x32_bf16(
                        ah8, bl8[fn][kk], acc[fm][fn], 0, 0, 0);
                    acc[fm][fn] = __builtin_amdgcn_mfma_f32_16x16x32_bf16(
                        al8, bh8[fn][kk], acc[fm][fn], 0, 0, 0);
                }
            }
        ushort* dh = wq ? kh : qh;
        ushort* dl = wq ? kl : ql;
        #pragma unroll
        for (int fm = 0; fm < 4; ++fm)
            #pragma unroll
            for (int fn = 0; fn < 2; ++fn) {
                int col = wn * 32 + fn * 16 + (lane & 15);
                float bv = bias[col];
                #pragma unroll
                for (int rr = 0; rr < 4; ++rr) {
                    int row = lt * 64 + fm * 16 + (lane >> 4) * 4 + rr;
                    int o = ((b * kH + h) * kL + row) * kDH + col;
                    float val = acc[fm][fn][rr] + bv;
                    ushort hh = f2bf(val);
                    dh[o] = hh;
                    dl[o] = f2bf(val - bf2f(hh));
                }
            }
    } else {
        // ---------------- xp branch (MFMA bf16, transposed store) ----------
        int bxp = blk - 512;
        int it = bxp >> 3, jt = bxp & 7;
        ushort (*xbs)[72] = (ushort(*)[72])smem;
        ushort (*wbs)[72] = (ushort(*)[72])(smem + 64 * 72 * 2);
        int r = tid >> 2, s = tid & 3;
        int wm = wave >> 1, wn = wave & 1;
        int am = wm * 32 + (lane & 15);
        int bn = wn * 32 + (lane & 15);
        int coff = (lane >> 4) * 8;
        f32x4 acc[2][2] = {};
        const float* xsrc = x + (size_t)(it * 64 + r) * kD + s * 16;
        const float* wsrc = Wp + (size_t)(jt * 64 + r) * kD + s * 16;
        for (int kt = 0; kt < 8; ++kt) {
            union { ushort u[16]; int4 v[2]; } px, pw;
            #pragma unroll
            for (int c4 = 0; c4 < 4; ++c4) {
                float4 fx = *(const float4*)(xsrc + kt * 64 + c4 * 4);
                float4 fw = *(const float4*)(wsrc + kt * 64 + c4 * 4);
                px.u[c4 * 4 + 0] = f2bf(fx.x); px.u[c4 * 4 + 1] = f2bf(fx.y);
                px.u[c4 * 4 + 2] = f2bf(fx.z); px.u[c4 * 4 + 3] = f2bf(fx.w);
                pw.u[c4 * 4 + 0] = f2bf(fw.x); pw.u[c4 * 4 + 1] = f2bf(fw.y);
                pw.u[c4 * 4 + 2] = f2bf(fw.z); pw.u[c4 * 4 + 3] = f2bf(fw.w);
            }
            __syncthreads();
            *(int4*)&xbs[r][s * 16] = px.v[0];
            *(int4*)&xbs[r][s * 16 + 8] = px.v[1];
            *(int4*)&wbs[r][s * 16] = pw.v[0];
            *(int4*)&wbs[r][s * 16 + 8] = pw.v[1];
            __syncthreads();
            #pragma unroll
            for (int kk = 0; kk < 2; ++kk) {
                bf16x8 af[2], bf[2];
                #pragma unroll
                for (int fm = 0; fm < 2; ++fm)
                    af[fm] = *(const bf16x8*)&xbs[am + fm * 16][kk * 32 + coff];
                #pragma unroll
                for (int fn = 0; fn < 2; ++fn)
                    bf[fn] = *(const bf16x8*)&wbs[bn + fn * 16][kk * 32 + coff];
                #pragma unroll
                for (int fm = 0; fm < 2; ++fm)
                    #pragma unroll
                    for (int fn = 0; fn < 2; ++fn)
                        acc[fm][fn] = __builtin_amdgcn_mfma_f32_16x16x32_bf16(
                            af[fm], bf[fn], acc[fm][fn], 0, 0, 0);
            }
        }
        #pragma unroll
        for (int fn = 0; fn < 2; ++fn) {
            int dcol = jt * 64 + wn * 32 + (lane & 15) + fn * 16;
            float bpv = bp[dcol];
            #pragma unroll
            for (int fm = 0; fm < 2; ++fm) {
                int l0 = it * 64 + wm * 32 + fm * 16 + (lane >> 4) * 4;
                union { ushort u[4]; uint2 v; } pk;
                #pragma unroll
                for (int rr = 0; rr < 4; ++rr)
                    pk.u[rr] = f2bf(acc[fm][fn][rr] + bpv);
                *(uint2*)&xpbT[(size_t)dcol * (size_t)(kB * kL) + l0] = pk.v;
            }
        }
    }
}

// ---------------------------------------------------------------------------
// K2 (MFMA, split-bf16): adj = gelu(q @ k^T) per (b,h). 64x64 tile, K=64.
// ---------------------------------------------------------------------------
__global__ __launch_bounds__(256) void k_adj(const ushort* __restrict__ qh,
        const ushort* __restrict__ ql, const ushort* __restrict__ kh,
        const ushort* __restrict__ kl, float* __restrict__ adj) {
    int blk = blockIdx.x;
    int bh = blk >> 6;
    int it = (blk >> 3) & 7, jt = blk & 7;
    __shared__ ushort ah[64][72], al[64][72];
    __shared__ ushort bh_[64][72], bl[64][72];
    int tid = threadIdx.x;
    int r = tid >> 2, s = tid & 3;
    size_t aoff = (size_t)(bh * kL + it * 64 + r) * kDH + s * 16;
    size_t boff = (size_t)(bh * kL + jt * 64 + r) * kDH + s * 16;
    *(int4*)&ah[r][s * 16]  = *(const int4*)&qh[aoff];
    *(int4*)&ah[r][s * 16 + 8]  = *(const int4*)&qh[aoff + 8];
    *(int4*)&al[r][s * 16]  = *(const int4*)&ql[aoff];
    *(int4*)&al[r][s * 16 + 8]  = *(const int4*)&ql[aoff + 8];
    *(int4*)&bh_[r][s * 16] = *(const int4*)&kh[boff];
    *(int4*)&bh_[r][s * 16 + 8] = *(const int4*)&kh[boff + 8];
    *(int4*)&bl[r][s * 16]  = *(const int4*)&kl[boff];
    *(int4*)&bl[r][s * 16 + 8]  = *(const int4*)&kl[boff + 8];
    __syncthreads();
    int lane = tid & 63, wave = tid >> 6;
    int wm = wave >> 1, wn = wave & 1;
    int am = wm * 32 + (lane & 15);
    int bn = wn * 32 + (lane & 15);
    int coff = (lane >> 4) * 8;
    f32x4 acc[2][2] = {};
    #pragma unroll
    for (int kk = 0; kk < 2; ++kk) {
        bf16x8 afh[2], afl[2], bfh[2], bfl[2];
        #pragma unroll
        for (int fm = 0; fm < 2; ++fm) {
            afh[fm] = *(const bf16x8*)&ah[am + fm * 16][kk * 32 + coff];
            afl[fm] = *(const bf16x8*)&al[am + fm * 16][kk * 32 + coff];
        }
        #pragma unroll
        for (int fn = 0; fn < 2; ++fn) {
            bfh[fn] = *(const bf16x8*)&bh_[bn + fn * 16][kk * 32 + coff];
            bfl[fn] = *(const bf16x8*)&bl[bn + fn * 16][kk * 32 + coff];
        }
        #pragma unroll
        for (int fm = 0; fm < 2; ++fm)
            #pragma unroll
            for (int fn = 0; fn < 2; ++fn) {
                acc[fm][fn] = __builtin_amdgcn_mfma_f32_16x16x32_bf16(
                    afh[fm], bfh[fn], acc[fm][fn], 0, 0, 0);
                acc[fm][fn] = __builtin_amdgcn_mfma_f32_16x16x32_bf16(
                    afh[fm], bfl[fn], acc[fm][fn], 0, 0, 0);
                acc[fm][fn] = __builtin_amdgcn_mfma_f32_16x16x32_bf16(
                    afl[fm], bfh[fn], acc[fm][fn], 0, 0, 0);
            }
    }
    int mrow = it * 64 + wm * 32 + (lane >> 4) * 4;
    int ncol = jt * 64 + wn * 32 + (lane & 15);
    #pragma unroll
    for (int fm = 0; fm < 2; ++fm)
        #pragma unroll
        for (int fn = 0; fn < 2; ++fn)
            #pragma unroll
            for (int rr = 0; rr < 4; ++rr)
                adj[((size_t)bh * kL + mrow + fm * 16 + rr) * kL + ncol + fn * 16] =
                    gelu_fast(acc[fm][fn][rr]);
}

// ---------------------------------------------------------------------------
// K3 (fused): TWO rows sequentially per wave (Wg fragments shared).
// Exact 256th-smallest via RADIX-4 ballot bisection (integer key space,
// -0.0 safe), boundary early-exits, integer extraction. Then threshold,
// logits, softmax-3, top-p, computed masks, row softmax (no max-subtract),
// bf16 adjb write. grid = ROWS/8.
// ---------------------------------------------------------------------------
__global__ __launch_bounds__(256) void k_select(const float* __restrict__ adj,
        const float* __restrict__ Wg,
        ushort* __restrict__ adjb,
        float* __restrict__ spbuf, float* __restrict__ entbuf) {
    int tid = threadIdx.x;
    int wave = tid >> 6, lane = tid & 63;
    int j0 = lane * 8;

    // Wg fragments (shared by this wave's rows -- same j0)
    union { float4 f4[2]; float f[8]; } wg0, wg1, wg2;
    wg0.f4[0] = *(const float4*)&Wg[j0];          wg0.f4[1] = *(const float4*)&Wg[j0 + 4];
    wg1.f4[0] = *(const float4*)&Wg[kL + j0];     wg1.f4[1] = *(const float4*)&Wg[kL + j0 + 4];
    wg2.f4[0] = *(const float4*)&Wg[2 * kL + j0]; wg2.f4[1] = *(const float4*)&Wg[2 * kL + j0 + 4];

    for (int rl = 0; rl < 2; ++rl) {
        int row = blockIdx.x * 8 + wave * 2 + rl;
        int i = row & (kL - 1);
        const float* arow = adj + (size_t)row * kL;

        float v[8];
        {
            float4 a0 = *(const float4*)&arow[j0];
            float4 a1 = *(const float4*)&arow[j0 + 4];
            v[0] = a0.x; v[1] = a0.y; v[2] = a0.z; v[3] = a0.w;
            v[4] = a1.x; v[5] = a1.y; v[6] = a1.z; v[7] = a1.w;
        }
        unsigned key[8];
        #pragma unroll
        for (int t = 0; t < 8; ++t) key[t] = mapf(v[t]);

        // radix-4 bisection, k = 255 (0-indexed), integer key space
        unsigned prefix = 0;
        int cbp = 0, cin = 512;
        int bit = 31;
        int mode = 0;               // 0: exhausted, 1: extract-min, 2: extract-max
        while (bit >= 1) {
            unsigned qsz = 1u << (bit - 1);
            unsigned q1 = prefix + qsz;
            unsigned q2 = prefix + 2u * qsz;
            unsigned q3 = prefix + 3u * qsz;
            int c1 = 0, c2 = 0, c3 = 0;
            #pragma unroll
            for (int t = 0; t < 8; ++t) {
                c1 += (int)__popcll(__ballot(key[t] < q1));
                c2 += (int)__popcll(__ballot(key[t] < q2));
                c3 += (int)__popcll(__ballot(key[t] < q3));
            }
            if (255 < c1)      { cin = c1 - cbp; }
            else if (255 < c2) { cin = c2 - c1;  prefix = q1; cbp = c1; }
            else if (255 < c3) { cin = c3 - c2;  prefix = q2; cbp = c2; }
            else               { cin = cin - (c3 - cbp); prefix = q3; cbp = c3; }
            bit -= 2;
            int loc = 255 - cbp;    // local rank of kth within interval
            if (cin == 1)        { mode = 2; break; }
            if (loc == 0)        { mode = 1; break; }
            if (loc == cin - 1)  { mode = 2; break; }
        }
        float thr;
        if (mode == 0) {
            thr = unmapf(prefix);   // all bits resolved: exact key
        } else {
            unsigned width = 1u << (bit + 1);   // bit in [-1,29]
            unsigned acc = (mode == 1) ? 0xFFFFFFFFu : 0u;
            #pragma unroll
            for (int t = 0; t < 8; ++t) {
                unsigned d = key[t] - prefix;
                bool mem = d < width;
                if (mode == 1) acc = (mem && key[t] < acc) ? key[t] : acc;
                else           acc = (mem && key[t] > acc) ? key[t] : acc;
            }
            if (mode == 1) {
                #pragma unroll
                for (int off = 1; off < 64; off <<= 1)
                    acc = min(acc, (unsigned)__shfl_xor((int)acc, off));
            } else {
                #pragma unroll
                for (int off = 1; off < 64; off <<= 1)
                    acc = max(acc, (unsigned)__shfl_xor((int)acc, off));
            }
            thr = unmapf(acc);
        }

        // threshold + logits
        float l0 = 0.f, l1 = 0.f, l2 = 0.f;
        #pragma unroll
        for (int t = 0; t < 8; ++t) {
            float nv = (v[t] > thr) ? v[t] : 0.0f;
            v[t] = nv;
            l0 = fmaf(nv, wg0.f[t], l0);
            l1 = fmaf(nv, wg1.f[t], l1);
            l2 = fmaf(nv, wg2.f[t], l2);
        }
        #pragma unroll
        for (int off = 1; off < 64; off <<= 1) {
            l0 += __shfl_xor(l0, off);
            l1 += __shfl_xor(l1, off);
            l2 += __shfl_xor(l2, off);
        }
        // softmax-3 + stable top-p (all lanes redundantly; wave-uniform)
        float m = fmaxf(l0, fmaxf(l1, l2));
        float e0 = __expf(l0 - m), e1 = __expf(l1 - m), e2 = __expf(l2 - m);
        float s = e0 + e1 + e2;
        float p[3] = {e0 / s, e1 / s, e2 / s};
        int o0, o1, o2;
        if (p[0] >= p[1] && p[0] >= p[2]) o0 = 0;
        else if (p[1] >= p[2]) o0 = 1;
        else o0 = 2;
        int r0 = (o0 == 0) ? 1 : 0;
        int r1 = (o0 == 2) ? 1 : 2;
        if (p[r0] >= p[r1]) { o1 = r0; o2 = r1; } else { o1 = r1; o2 = r0; }
        float sp0 = p[o0], sp1 = p[o1], sp2 = p[o2];
        float c0 = sp0, c1 = sp0 + sp1, c2 = c1 + sp2;
        bool m0 = c0 > 0.5f, m1 = c1 > 0.5f, m2 = c2 > 0.5f;
        int ti = m0 ? 0 : (m1 ? 1 : 2);
        bool mm0 = m0 && (ti != 0);
        bool mm1 = m1 && (ti != 1);
        bool mm2 = m2 && (ti != 2);
        float g[3] = {0.f, 0.f, 0.f};
        g[o0] = mm0 ? 0.f : 1.f;
        g[o1] = mm1 ? 0.f : 1.f;
        g[o2] = mm2 ? 0.f : 1.f;
        if (lane == 0) {
            spbuf[row * 3 + 0] = mm0 ? 0.f : sp0;
            spbuf[row * 3 + 1] = mm1 ? 0.f : sp1;
            spbuf[row * 3 + 2] = mm2 ? 0.f : sp2;
            entbuf[row] = p[0] * __logf(p[0] + 1e-10f) +
                          p[1] * __logf(p[1] + 1e-10f) +
                          p[2] * __logf(p[2] + 1e-10f);
        }

        // computed masks: S (same mod-64 residue, j!=i) -> g0; T (same
        // 64-block, incl diag) -> g1 (+1 on diag); else -> g2
        int i6 = i >> 6, i63 = i & 63;
        bool inb = ((lane >> 3) == i6);         // lane's 8 elems share j>>6
        float sel1 = inb ? (g[1] + 1.0f) : g[0];
        float sel0 = inb ? g[1] : g[2];
        int lane8 = (lane & 7) * 8;
        // row softmax without max-subtract (|av| <= ~30 -> exp safe in fp32)
        float e[8], ls = 0.f;
        #pragma unroll
        for (int t = 0; t < 8; ++t) {
            bool ing = (lane8 + t) == i63;
            float av = v[t] * (ing ? sel1 : sel0);
            e[t] = __expf(av);
            ls += e[t];
        }
        #pragma unroll
        for (int off = 1; off < 64; off <<= 1) ls += __shfl_xor(ls, off);
        float inv = 1.0f / ls;
        union { ushort u[8]; int4 vv; } pk;
        #pragma unroll
        for (int t = 0; t < 8; ++t) pk.u[t] = f2bf(e[t] * inv);
        *(int4*)&adjb[(size_t)row * kL + j0] = pk.vv;
    }
}

// ---------------------------------------------------------------------------
// K6 (merged): blocks 0..511: out = adjb @ xpbT (MFMA);
// blocks 512..549: loss stage 1 (imps col-sums + entropy partials).
// ---------------------------------------------------------------------------
__global__ __launch_bounds__(256) void k_out_loss1(const ushort* __restrict__ adjb,
        const ushort* __restrict__ xpbT, float* __restrict__ out,
        const float* __restrict__ spbuf, const float* __restrict__ entbuf,
        float* __restrict__ imps_buf, float* __restrict__ entpart) {
    int tid = threadIdx.x;
    int blk = blockIdx.x;
    if (blk < 512) {
        // ---------------- out branch ----------------
        __shared__ ushort as_[64][72];
        __shared__ ushort bs_[64][72];
        int bh = blk >> 3, it = blk & 7;
        int b = bh >> 3, h = bh & 7;
        int lane = tid & 63, wave = tid >> 6;
        int wm = wave >> 1, wn = wave & 1;
        int r = tid >> 2, s = tid & 3;
        const ushort* aG = adjb + ((size_t)(bh * kL + it * 64 + r)) * kL + s * 16;
        const ushort* bG = xpbT + ((size_t)(h * kDH + r)) * (size_t)(kB * kL) + b * kL + s * 16;
        f32x4 acc[2][2] = {};
        int am = wm * 32 + (lane & 15);
        int bn = wn * 32 + (lane & 15);
        int coff = (lane >> 4) * 8;
        for (int kt = 0; kt < 8; ++kt) {
            int4 a0 = *(const int4*)(aG + kt * 64);
            int4 a1 = *(const int4*)(aG + kt * 64 + 8);
            int4 b0 = *(const int4*)(bG + kt * 64);
            int4 b1 = *(const int4*)(bG + kt * 64 + 8);
            __syncthreads();
            *(int4*)&as_[r][s * 16] = a0;
            *(int4*)&as_[r][s * 16 + 8] = a1;
            *(int4*)&bs_[r][s * 16] = b0;
            *(int4*)&bs_[r][s * 16 + 8] = b1;
            __syncthreads();
            #pragma unroll
            for (int kk = 0; kk < 2; ++kk) {
                bf16x8 af[2], bf[2];
                #pragma unroll
                for (int fm = 0; fm < 2; ++fm)
                    af[fm] = *(const bf16x8*)&as_[am + fm * 16][kk * 32 + coff];
                #pragma unroll
                for (int fn = 0; fn < 2; ++fn)
                    bf[fn] = *(const bf16x8*)&bs_[bn + fn * 16][kk * 32 + coff];
                #pragma unroll
                for (int fm = 0; fm < 2; ++fm)
                    #pragma unroll
                    for (int fn = 0; fn < 2; ++fn)
                        acc[fm][fn] = __builtin_amdgcn_mfma_f32_16x16x32_bf16(
                            af[fm], bf[fn], acc[fm][fn], 0, 0, 0);
            }
        }
        int mrow = it * 64 + wm * 32 + (lane >> 4) * 4;
        int ncol = h * kDH + wn * 32 + (lane & 15);
        #pragma unroll
        for (int fm = 0; fm < 2; ++fm)
            #pragma unroll
            for (int fn = 0; fn < 2; ++fn)
                #pragma unroll
                for (int rr = 0; rr < 4; ++rr)
                    out[((size_t)b * kL + mrow + fm * 16 + rr) * kD + ncol + fn * 16] =
                        acc[fm][fn][rr];
    } else {
        // ---------------- loss stage 1 branch ----------------
        int lb = blk - 512;
        if (lb < 6) {
            int idx = lb * 256 + tid;      // < 1536
            float s = 0.f;
            for (int bh = 0; bh < kBH; ++bh)
                s += spbuf[bh * (kL * 3) + idx];
            imps_buf[idx] = s;
        } else {
            int eb = lb - 6;               // 0..31
            const float* src = entbuf + eb * 1024 + tid * 4;
            float4 v4 = *(const float4*)src;
            float s = v4.x + v4.y + v4.z + v4.w;
            __shared__ float red[256];
            red[tid] = s;
            __syncthreads();
            for (int st = 128; st > 0; st >>= 1) {
                if (tid < st) red[tid] += red[tid + st];
                __syncthreads();
            }
            if (tid == 0) entpart[eb] = red[0];
        }
    }
}

// ---------------------------------------------------------------------------
// K7b: loss stage 2 (single block): mean/var of imps (ddof=1) + entropy total
// ---------------------------------------------------------------------------
__global__ __launch_bounds__(256) void k_loss2(const float* __restrict__ imps_buf,
        const float* __restrict__ entpart, float* __restrict__ out_loss) {
    __shared__ float red[256];
    int tid = threadIdx.x;
    float im[6];
    #pragma unroll
    for (int t = 0; t < 6; ++t) im[t] = imps_buf[t * 256 + tid];
    float ms = im[0] + im[1] + im[2] + im[3] + im[4] + im[5];
    red[tid] = ms;
    __syncthreads();
    for (int st = 128; st > 0; st >>= 1) {
        if (tid < st) red[tid] += red[tid + st];
        __syncthreads();
    }
    float mean = red[0] / (float)(kL * 3);
    __syncthreads();
    float vs = 0.f;
    #pragma unroll
    for (int t = 0; t < 6; ++t) { float d = im[t] - mean; vs = fmaf(d, d, vs); }
    red[tid] = vs;
    __syncthreads();
    for (int st = 128; st > 0; st >>= 1) {
        if (tid < st) red[tid] += red[tid + st];
        __syncthreads();
    }
    float var = red[0] / (float)(kL * 3 - 1);
    __syncthreads();
    red[tid] = (tid < 32) ? entpart[tid] : 0.f;
    __syncthreads();
    for (int st = 128; st > 0; st >>= 1) {
        if (tid < st) red[tid] += red[tid + st];
        __syncthreads();
    }
    if (tid == 0) {
        float loss_imp = var / (mean * mean + 1e-10f);
        float loss_dyn = -red[0] / (float)(kBH * 3);
        out_loss[0] = loss_imp + 0.1f * loss_dyn;
    }
}

// ---------------------------------------------------------------------------
extern "C" void kernel_launch(void* const* d_in, const int* in_sizes, int n_in,
                              void* d_out, int out_size, void* d_ws, size_t ws_size,
                              hipStream_t stream) {
    const float* x     = (const float*)d_in[0];
    const float* W1    = (const float*)d_in[2];
    const float* b1    = (const float*)d_in[3];
    const float* W2    = (const float*)d_in[4];
    const float* b2    = (const float*)d_in[5];
    const float* Wg    = (const float*)d_in[6];
    const float* Wp    = (const float*)d_in[7];
    const float* bp    = (const float*)d_in[8];
    float* out = (float*)d_out;
    float* ws  = (float*)d_ws;

    // workspace layout (float units). adjb overlays qh/ql/kh/kl (dead after
    // k_adj; stream order serializes k_adj -> k_select).
    float*  adj    = ws;                          // [0, 16777216)
    ushort* qh     = (ushort*)(ws + 16777216);
    ushort* ql     = (ushort*)(ws + 17825792);
    ushort* kh     = (ushort*)(ws + 18874368);
    ushort* kl     = (ushort*)(ws + 19922944);
    ushort* adjb   = (ushort*)(ws + 16777216);    // overlays qh..kl + extra
    ushort* xpbT   = (ushort*)(ws + 25165824);
    float*  spbuf  = ws + 26214400;               // 98,304
    float*  entbuf = ws + 26312704;               // 32,768
    float*  imps_b = ws + 26345472;               // 1,536
    float*  entprt = ws + 26347008;               // 32

    k_qk_xp<<<1024, 256, 0, stream>>>(x, W1, b1, W2, b2, Wp, bp,
                                      qh, ql, kh, kl, xpbT);
    k_adj<<<kBH * 64, 256, 0, stream>>>(qh, ql, kh, kl, adj);
    k_select<<<kROWS / 8, 256, 0, stream>>>(adj, Wg, adjb, spbuf, entbuf);
    k_out_loss1<<<550, 256, 0, stream>>>(adjb, xpbT, out, spbuf, entbuf,
                                         imps_b, entprt);
    k_loss2<<<1, 256, 0, stream>>>(imps_b, entprt, out + (size_t)kB * kL * kD);
}

// Round 17
// 101.940 us; speedup vs baseline: 1.0184x; 1.0184x over previous
//
#include <hip/hip_runtime.h>
#include <hip/hip_bf16.h>
#include <math.h>

// Problem constants
static constexpr int kB = 8;
static constexpr int kH = 8;
static constexpr int kL = 512;
static constexpr int kD = 512;
static constexpr int kDH = 64;     // D/H
static constexpr int kBH = 64;     // B*H
static constexpr int kROWS = kBH * kL;  // 32768

typedef short bf16x8 __attribute__((ext_vector_type(8)));
typedef float f32x4 __attribute__((ext_vector_type(4)));

// RNE float->bf16 (finite inputs only)
__device__ __forceinline__ ushort f2bf(float f) {
    unsigned u = __float_as_uint(f);
    unsigned r = u + 0x7fffu + ((u >> 16) & 1u);
    return (ushort)(r >> 16);
}
__device__ __forceinline__ float bf2f(ushort h) {
    return __uint_as_float((unsigned)h << 16);
}
// order-isomorphic float<->uint maps (finite, no NaN; -0.0 < +0.0 in key order)
__device__ __forceinline__ unsigned mapf(float f) {
    unsigned u = __float_as_uint(f);
    return (u & 0x80000000u) ? ~u : (u | 0x80000000u);
}
__device__ __forceinline__ float unmapf(unsigned u) {
    return (u & 0x80000000u) ? __uint_as_float(u ^ 0x80000000u)
                             : __uint_as_float(~u);
}

// gelu with A&S 7.1.26 erf (max abs err ~1.5e-7, monotone-preserving)
__device__ __forceinline__ float gelu_fast(float v) {
    float z = v * 0.70710678118654752440f;
    float az = fabsf(z);
    float t = 1.0f / (1.0f + 0.3275911f * az);
    float ex = __expf(-az * az);
    float poly = t * (0.254829592f + t * (-0.284496736f + t * (1.421413741f +
                 t * (-1.453152027f + t * 1.061405429f))));
    float erfv = 1.0f - poly * ex;
    erfv = (z < 0.0f) ? -erfv : erfv;
    return 0.5f * v * (1.0f + erfv);
}

// ---------------------------------------------------------------------------
// K1 (merged): blocks 0..511: q/k projection (split-bf16 MFMA, hi/lo out);
// blocks 512..1023: xp = x @ Wp^T + bp -> transposed bf16 xpbT (MFMA).
// Both branches only read x + weights (independent). LDS aliased (18.4 KB).
// ---------------------------------------------------------------------------
__global__ __launch_bounds__(256) void k_qk_xp(const float* __restrict__ x,
        const float* __restrict__ W1, const float* __restrict__ b1,
        const float* __restrict__ W2, const float* __restrict__ b2,
        const float* __restrict__ Wp, const float* __restrict__ bp,
        ushort* __restrict__ qh, ushort* __restrict__ ql,
        ushort* __restrict__ kh, ushort* __restrict__ kl,
        ushort* __restrict__ xpbT) {
    __shared__ __align__(16) char smem[2 * 64 * 72 * 2];
    int tid = threadIdx.x;
    int blk = blockIdx.x;
    int lane = tid & 63, wave = tid >> 6;
    if (blk < 512) {
        // ------- qk branch (split-bf16 MFMA; q||k, 4 waves: wq x wn) -------
        int b = blk >> 6, h = (blk >> 3) & 7, lt = blk & 7;
        ushort (*xhi)[72] = (ushort(*)[72])smem;
        ushort (*xlo)[72] = (ushort(*)[72])(smem + 64 * 72 * 2);
        {
            int r = tid >> 2, s = tid & 3;
            const float* src = x + (size_t)(b * kL + lt * 64 + r) * kD + h * kDH + s * 16;
            union { ushort u[16]; int4 v[2]; } ph, pl;
            #pragma unroll
            for (int c4 = 0; c4 < 4; ++c4) {
                float4 f = *(const float4*)(src + c4 * 4);
                float fv[4] = {f.x, f.y, f.z, f.w};
                #pragma unroll
                for (int t = 0; t < 4; ++t) {
                    ushort hh = f2bf(fv[t]);
                    ph.u[c4 * 4 + t] = hh;
                    pl.u[c4 * 4 + t] = f2bf(fv[t] - bf2f(hh));
                }
            }
            *(int4*)&xhi[r][s * 16] = ph.v[0];
            *(int4*)&xhi[r][s * 16 + 8] = ph.v[1];
            *(int4*)&xlo[r][s * 16] = pl.v[0];
            *(int4*)&xlo[r][s * 16 + 8] = pl.v[1];
        }
        int wq = wave >> 1, wn = wave & 1;
        const float* Wm = wq ? W2 : W1;
        const float* bias = wq ? b2 : b1;
        int coff = (lane >> 4) * 8;
        // B fragments from global (L2-resident), on-the-fly hi/lo split
        bf16x8 bh8[2][2], bl8[2][2];   // [fn][kk]
        #pragma unroll
        for (int fn = 0; fn < 2; ++fn) {
            int browg = wn * 32 + fn * 16 + (lane & 15);
            #pragma unroll
            for (int kk = 0; kk < 2; ++kk) {
                const float* wsrc = Wm + browg * 64 + kk * 32 + coff;
                float4 f0 = *(const float4*)(wsrc);
                float4 f1 = *(const float4*)(wsrc + 4);
                float fv[8] = {f0.x, f0.y, f0.z, f0.w, f1.x, f1.y, f1.z, f1.w};
                union { ushort u[8]; bf16x8 v; } uh, ul;
                #pragma unroll
                for (int t = 0; t < 8; ++t) {
                    ushort hh = f2bf(fv[t]);
                    uh.u[t] = hh;
                    ul.u[t] = f2bf(fv[t] - bf2f(hh));
                }
                bh8[fn][kk] = uh.v;
                bl8[fn][kk] = ul.v;
            }
        }
        __syncthreads();
        f32x4 acc[4][2] = {};
        #pragma unroll
        for (int kk = 0; kk < 2; ++kk)
            #pragma unroll
            for (int fm = 0; fm < 4; ++fm) {
                bf16x8 ah8 = *(const bf16x8*)&xhi[fm * 16 + (lane & 15)][kk * 32 + coff];
                bf16x8 al8 = *(const bf16x8*)&xlo[fm * 16 + (lane & 15)][kk * 32 + coff];
                #pragma unroll
                for (int fn = 0; fn < 2; ++fn) {
                    acc[fm][fn] = __builtin_amdgcn_mfma_f32_16x16x32_bf16(
                        ah8, bh8[fn][kk], acc[fm][fn], 0, 0, 0);
                    acc[fm][fn] = __builtin_amdgcn_mfma_f32_16x16x32_bf16(
                        ah8, bl8[fn][kk], acc[fm][fn], 0, 0, 0);
                    acc[fm][fn] = __builtin_amdgcn_mfma_f32_16x16x32_bf16(
                        al8, bh8[fn][kk], acc[fm][fn], 0, 0, 0);
                }
            }
        ushort* dh = wq ? kh : qh;
        ushort* dl = wq ? kl : ql;
        #pragma unroll
        for (int fm = 0; fm < 4; ++fm)
            #pragma unroll
            for (int fn = 0; fn < 2; ++fn) {
                int col = wn * 32 + fn * 16 + (lane & 15);
                float bv = bias[col];
                #pragma unroll
                for (int rr = 0; rr < 4; ++rr) {
                    int row = lt * 64 + fm * 16 + (lane >> 4) * 4 + rr;
                    int o = ((b * kH + h) * kL + row) * kDH + col;
                    float val = acc[fm][fn][rr] + bv;
                    ushort hh = f2bf(val);
                    dh[o] = hh;
                    dl[o] = f2bf(val - bf2f(hh));
                }
            }
    } else {
        // ---------------- xp branch (MFMA bf16, transposed store) ----------
        int bxp = blk - 512;
        int it = bxp >> 3, jt = bxp & 7;
        ushort (*xbs)[72] = (ushort(*)[72])smem;
        ushort (*wbs)[72] = (ushort(*)[72])(smem + 64 * 72 * 2);
        int r = tid >> 2, s = tid & 3;
        int wm = wave >> 1, wn = wave & 1;
        int am = wm * 32 + (lane & 15);
        int bn = wn * 32 + (lane & 15);
        int coff = (lane >> 4) * 8;
        f32x4 acc[2][2] = {};
        const float* xsrc = x + (size_t)(it * 64 + r) * kD + s * 16;
        const float* wsrc = Wp + (size_t)(jt * 64 + r) * kD + s * 16;
        for (int kt = 0; kt < 8; ++kt) {
            union { ushort u[16]; int4 v[2]; } px, pw;
            #pragma unroll
            for (int c4 = 0; c4 < 4; ++c4) {
                float4 fx = *(const float4*)(xsrc + kt * 64 + c4 * 4);
                float4 fw = *(const float4*)(wsrc + kt * 64 + c4 * 4);
                px.u[c4 * 4 + 0] = f2bf(fx.x); px.u[c4 * 4 + 1] = f2bf(fx.y);
                px.u[c4 * 4 + 2] = f2bf(fx.z); px.u[c4 * 4 + 3] = f2bf(fx.w);
                pw.u[c4 * 4 + 0] = f2bf(fw.x); pw.u[c4 * 4 + 1] = f2bf(fw.y);
                pw.u[c4 * 4 + 2] = f2bf(fw.z); pw.u[c4 * 4 + 3] = f2bf(fw.w);
            }
            __syncthreads();
            *(int4*)&xbs[r][s * 16] = px.v[0];
            *(int4*)&xbs[r][s * 16 + 8] = px.v[1];
            *(int4*)&wbs[r][s * 16] = pw.v[0];
            *(int4*)&wbs[r][s * 16 + 8] = pw.v[1];
            __syncthreads();
            #pragma unroll
            for (int kk = 0; kk < 2; ++kk) {
                bf16x8 af[2], bf[2];
                #pragma unroll
                for (int fm = 0; fm < 2; ++fm)
                    af[fm] = *(const bf16x8*)&xbs[am + fm * 16][kk * 32 + coff];
                #pragma unroll
                for (int fn = 0; fn < 2; ++fn)
                    bf[fn] = *(const bf16x8*)&wbs[bn + fn * 16][kk * 32 + coff];
                #pragma unroll
                for (int fm = 0; fm < 2; ++fm)
                    #pragma unroll
                    for (int fn = 0; fn < 2; ++fn)
                        acc[fm][fn] = __builtin_amdgcn_mfma_f32_16x16x32_bf16(
                            af[fm], bf[fn], acc[fm][fn], 0, 0, 0);
            }
        }
        #pragma unroll
        for (int fn = 0; fn < 2; ++fn) {
            int dcol = jt * 64 + wn * 32 + (lane & 15) + fn * 16;
            float bpv = bp[dcol];
            #pragma unroll
            for (int fm = 0; fm < 2; ++fm) {
                int l0 = it * 64 + wm * 32 + fm * 16 + (lane >> 4) * 4;
                union { ushort u[4]; uint2 v; } pk;
                #pragma unroll
                for (int rr = 0; rr < 4; ++rr)
                    pk.u[rr] = f2bf(acc[fm][fn][rr] + bpv);
                *(uint2*)&xpbT[(size_t)dcol * (size_t)(kB * kL) + l0] = pk.v;
            }
        }
    }
}

// ---------------------------------------------------------------------------
// K2 (MFMA, split-bf16): adj = gelu(q @ k^T) per (b,h). 64x64 tile, K=64.
// ---------------------------------------------------------------------------
__global__ __launch_bounds__(256) void k_adj(const ushort* __restrict__ qh,
        const ushort* __restrict__ ql, const ushort* __restrict__ kh,
        const ushort* __restrict__ kl, float* __restrict__ adj) {
    int blk = blockIdx.x;
    int bh = blk >> 6;
    int it = (blk >> 3) & 7, jt = blk & 7;
    __shared__ ushort ah[64][72], al[64][72];
    __shared__ ushort bh_[64][72], bl[64][72];
    int tid = threadIdx.x;
    int r = tid >> 2, s = tid & 3;
    size_t aoff = (size_t)(bh * kL + it * 64 + r) * kDH + s * 16;
    size_t boff = (size_t)(bh * kL + jt * 64 + r) * kDH + s * 16;
    *(int4*)&ah[r][s * 16]  = *(const int4*)&qh[aoff];
    *(int4*)&ah[r][s * 16 + 8]  = *(const int4*)&qh[aoff + 8];
    *(int4*)&al[r][s * 16]  = *(const int4*)&ql[aoff];
    *(int4*)&al[r][s * 16 + 8]  = *(const int4*)&ql[aoff + 8];
    *(int4*)&bh_[r][s * 16] = *(const int4*)&kh[boff];
    *(int4*)&bh_[r][s * 16 + 8] = *(const int4*)&kh[boff + 8];
    *(int4*)&bl[r][s * 16]  = *(const int4*)&kl[boff];
    *(int4*)&bl[r][s * 16 + 8]  = *(const int4*)&kl[boff + 8];
    __syncthreads();
    int lane = tid & 63, wave = tid >> 6;
    int wm = wave >> 1, wn = wave & 1;
    int am = wm * 32 + (lane & 15);
    int bn = wn * 32 + (lane & 15);
    int coff = (lane >> 4) * 8;
    f32x4 acc[2][2] = {};
    #pragma unroll
    for (int kk = 0; kk < 2; ++kk) {
        bf16x8 afh[2], afl[2], bfh[2], bfl[2];
        #pragma unroll
        for (int fm = 0; fm < 2; ++fm) {
            afh[fm] = *(const bf16x8*)&ah[am + fm * 16][kk * 32 + coff];
            afl[fm] = *(const bf16x8*)&al[am + fm * 16][kk * 32 + coff];
        }
        #pragma unroll
        for (int fn = 0; fn < 2; ++fn) {
            bfh[fn] = *(const bf16x8*)&bh_[bn + fn * 16][kk * 32 + coff];
            bfl[fn] = *(const bf16x8*)&bl[bn + fn * 16][kk * 32 + coff];
        }
        #pragma unroll
        for (int fm = 0; fm < 2; ++fm)
            #pragma unroll
            for (int fn = 0; fn < 2; ++fn) {
                acc[fm][fn] = __builtin_amdgcn_mfma_f32_16x16x32_bf16(
                    afh[fm], bfh[fn], acc[fm][fn], 0, 0, 0);
                acc[fm][fn] = __builtin_amdgcn_mfma_f32_16x16x32_bf16(
                    afh[fm], bfl[fn], acc[fm][fn], 0, 0, 0);
                acc[fm][fn] = __builtin_amdgcn_mfma_f32_16x16x32_bf16(
                    afl[fm], bfh[fn], acc[fm][fn], 0, 0, 0);
            }
    }
    int mrow = it * 64 + wm * 32 + (lane >> 4) * 4;
    int ncol = jt * 64 + wn * 32 + (lane & 15);
    #pragma unroll
    for (int fm = 0; fm < 2; ++fm)
        #pragma unroll
        for (int fn = 0; fn < 2; ++fn)
            #pragma unroll
            for (int rr = 0; rr < 4; ++rr)
                adj[((size_t)bh * kL + mrow + fm * 16 + rr) * kL + ncol + fn * 16] =
                    gelu_fast(acc[fm][fn][rr]);
}

// ---------------------------------------------------------------------------
// K3 (fused): per-row, one wave. Exact 256th-smallest via RADIX-4 ballot
// bisection (integer key space, -0.0 safe), boundary early-exits, integer
// extraction. Then threshold, logits, softmax-3, top-p, computed masks,
// row softmax (no max-subtract), bf16 adjb write. grid = ROWS/4.
// ---------------------------------------------------------------------------
__global__ __launch_bounds__(256) void k_select(const float* __restrict__ adj,
        const float* __restrict__ Wg,
        ushort* __restrict__ adjb,
        float* __restrict__ spbuf, float* __restrict__ entbuf) {
    int tid = threadIdx.x;
    int wave = tid >> 6, lane = tid & 63;
    int row = blockIdx.x * 4 + wave;
    int i = row & (kL - 1);
    const float* arow = adj + (size_t)row * kL;
    int j0 = lane * 8;

    float v[8];
    {
        float4 a0 = *(const float4*)&arow[j0];
        float4 a1 = *(const float4*)&arow[j0 + 4];
        v[0] = a0.x; v[1] = a0.y; v[2] = a0.z; v[3] = a0.w;
        v[4] = a1.x; v[5] = a1.y; v[6] = a1.z; v[7] = a1.w;
    }
    unsigned key[8];
    #pragma unroll
    for (int t = 0; t < 8; ++t) key[t] = mapf(v[t]);

    // radix-4 bisection, k = 255 (0-indexed), integer key space
    unsigned prefix = 0;
    int cbp = 0, cin = 512;
    int bit = 31;
    int mode = 0;                   // 0: exhausted, 1: extract-min, 2: extract-max
    while (bit >= 1) {
        unsigned qsz = 1u << (bit - 1);
        unsigned q1 = prefix + qsz;
        unsigned q2 = prefix + 2u * qsz;
        unsigned q3 = prefix + 3u * qsz;
        int c1 = 0, c2 = 0, c3 = 0;
        #pragma unroll
        for (int t = 0; t < 8; ++t) {
            c1 += (int)__popcll(__ballot(key[t] < q1));
            c2 += (int)__popcll(__ballot(key[t] < q2));
            c3 += (int)__popcll(__ballot(key[t] < q3));
        }
        if (255 < c1)      { cin = c1 - cbp; }
        else if (255 < c2) { cin = c2 - c1;  prefix = q1; cbp = c1; }
        else if (255 < c3) { cin = c3 - c2;  prefix = q2; cbp = c2; }
        else               { cin = cin - (c3 - cbp); prefix = q3; cbp = c3; }
        bit -= 2;
        int loc = 255 - cbp;        // local rank of kth within interval
        if (cin == 1)        { mode = 2; break; }
        if (loc == 0)        { mode = 1; break; }
        if (loc == cin - 1)  { mode = 2; break; }
    }
    float thr;
    if (mode == 0) {
        thr = unmapf(prefix);       // all bits resolved: exact key
    } else {
        unsigned width = 1u << (bit + 1);   // bit in [-1,29]
        unsigned acc = (mode == 1) ? 0xFFFFFFFFu : 0u;
        #pragma unroll
        for (int t = 0; t < 8; ++t) {
            unsigned d = key[t] - prefix;
            bool mem = d < width;
            if (mode == 1) acc = (mem && key[t] < acc) ? key[t] : acc;
            else           acc = (mem && key[t] > acc) ? key[t] : acc;
        }
        if (mode == 1) {
            #pragma unroll
            for (int off = 1; off < 64; off <<= 1)
                acc = min(acc, (unsigned)__shfl_xor((int)acc, off));
        } else {
            #pragma unroll
            for (int off = 1; off < 64; off <<= 1)
                acc = max(acc, (unsigned)__shfl_xor((int)acc, off));
        }
        thr = unmapf(acc);
    }

    // threshold + logits (Wg as float4)
    union { float4 f4[2]; float f[8]; } wg0, wg1, wg2;
    wg0.f4[0] = *(const float4*)&Wg[j0];          wg0.f4[1] = *(const float4*)&Wg[j0 + 4];
    wg1.f4[0] = *(const float4*)&Wg[kL + j0];     wg1.f4[1] = *(const float4*)&Wg[kL + j0 + 4];
    wg2.f4[0] = *(const float4*)&Wg[2 * kL + j0]; wg2.f4[1] = *(const float4*)&Wg[2 * kL + j0 + 4];
    float l0 = 0.f, l1 = 0.f, l2 = 0.f;
    #pragma unroll
    for (int t = 0; t < 8; ++t) {
        float nv = (v[t] > thr) ? v[t] : 0.0f;
        v[t] = nv;
        l0 = fmaf(nv, wg0.f[t], l0);
        l1 = fmaf(nv, wg1.f[t], l1);
        l2 = fmaf(nv, wg2.f[t], l2);
    }
    #pragma unroll
    for (int off = 1; off < 64; off <<= 1) {
        l0 += __shfl_xor(l0, off);
        l1 += __shfl_xor(l1, off);
        l2 += __shfl_xor(l2, off);
    }
    // softmax-3 + stable top-p (all lanes redundantly; wave-uniform)
    float m = fmaxf(l0, fmaxf(l1, l2));
    float e0 = __expf(l0 - m), e1 = __expf(l1 - m), e2 = __expf(l2 - m);
    float s = e0 + e1 + e2;
    float p[3] = {e0 / s, e1 / s, e2 / s};
    int o0, o1, o2;
    if (p[0] >= p[1] && p[0] >= p[2]) o0 = 0;
    else if (p[1] >= p[2]) o0 = 1;
    else o0 = 2;
    int r0 = (o0 == 0) ? 1 : 0;
    int r1 = (o0 == 2) ? 1 : 2;
    if (p[r0] >= p[r1]) { o1 = r0; o2 = r1; } else { o1 = r1; o2 = r0; }
    float sp0 = p[o0], sp1 = p[o1], sp2 = p[o2];
    float c0 = sp0, c1 = sp0 + sp1, c2 = c1 + sp2;
    bool m0 = c0 > 0.5f, m1 = c1 > 0.5f, m2 = c2 > 0.5f;
    int ti = m0 ? 0 : (m1 ? 1 : 2);
    bool mm0 = m0 && (ti != 0);
    bool mm1 = m1 && (ti != 1);
    bool mm2 = m2 && (ti != 2);
    float g[3] = {0.f, 0.f, 0.f};
    g[o0] = mm0 ? 0.f : 1.f;
    g[o1] = mm1 ? 0.f : 1.f;
    g[o2] = mm2 ? 0.f : 1.f;
    if (lane == 0) {
        spbuf[row * 3 + 0] = mm0 ? 0.f : sp0;
        spbuf[row * 3 + 1] = mm1 ? 0.f : sp1;
        spbuf[row * 3 + 2] = mm2 ? 0.f : sp2;
        entbuf[row] = p[0] * __logf(p[0] + 1e-10f) +
                      p[1] * __logf(p[1] + 1e-10f) +
                      p[2] * __logf(p[2] + 1e-10f);
    }

    // computed masks: S (same mod-64 residue, j!=i) -> g0; T (same 64-block,
    // incl diag) -> g1 (+1 on diag); else -> g2
    int i6 = i >> 6, i63 = i & 63;
    bool inb = ((lane >> 3) == i6);             // lane's 8 elems share j>>6
    float sel1 = inb ? (g[1] + 1.0f) : g[0];
    float sel0 = inb ? g[1] : g[2];
    int lane8 = (lane & 7) * 8;
    // row softmax without max-subtract (|av| <= ~30 -> exp safe in fp32)
    float e[8], ls = 0.f;
    #pragma unroll
    for (int t = 0; t < 8; ++t) {
        bool ing = (lane8 + t) == i63;
        float av = v[t] * (ing ? sel1 : sel0);
        e[t] = __expf(av);
        ls += e[t];
    }
    #pragma unroll
    for (int off = 1; off < 64; off <<= 1) ls += __shfl_xor(ls, off);
    float inv = 1.0f / ls;
    union { ushort u[8]; int4 vv; } pk;
    #pragma unroll
    for (int t = 0; t < 8; ++t) pk.u[t] = f2bf(e[t] * inv);
    *(int4*)&adjb[(size_t)row * kL + j0] = pk.vv;
}

// ---------------------------------------------------------------------------
// K6 (merged): blocks 0..511: out = adjb @ xpbT (MFMA);
// blocks 512..549: loss stage 1 (imps col-sums + entropy partials).
// ---------------------------------------------------------------------------
__global__ __launch_bounds__(256) void k_out_loss1(const ushort* __restrict__ adjb,
        const ushort* __restrict__ xpbT, float* __restrict__ out,
        const float* __restrict__ spbuf, const float* __restrict__ entbuf,
        float* __restrict__ imps_buf, float* __restrict__ entpart) {
    int tid = threadIdx.x;
    int blk = blockIdx.x;
    if (blk < 512) {
        // ---------------- out branch ----------------
        __shared__ ushort as_[64][72];
        __shared__ ushort bs_[64][72];
        int bh = blk >> 3, it = blk & 7;
        int b = bh >> 3, h = bh & 7;
        int lane = tid & 63, wave = tid >> 6;
        int wm = wave >> 1, wn = wave & 1;
        int r = tid >> 2, s = tid & 3;
        const ushort* aG = adjb + ((size_t)(bh * kL + it * 64 + r)) * kL + s * 16;
        const ushort* bG = xpbT + ((size_t)(h * kDH + r)) * (size_t)(kB * kL) + b * kL + s * 16;
        f32x4 acc[2][2] = {};
        int am = wm * 32 + (lane & 15);
        int bn = wn * 32 + (lane & 15);
        int coff = (lane >> 4) * 8;
        for (int kt = 0; kt < 8; ++kt) {
            int4 a0 = *(const int4*)(aG + kt * 64);
            int4 a1 = *(const int4*)(aG + kt * 64 + 8);
            int4 b0 = *(const int4*)(bG + kt * 64);
            int4 b1 = *(const int4*)(bG + kt * 64 + 8);
            __syncthreads();
            *(int4*)&as_[r][s * 16] = a0;
            *(int4*)&as_[r][s * 16 + 8] = a1;
            *(int4*)&bs_[r][s * 16] = b0;
            *(int4*)&bs_[r][s * 16 + 8] = b1;
            __syncthreads();
            #pragma unroll
            for (int kk = 0; kk < 2; ++kk) {
                bf16x8 af[2], bf[2];
                #pragma unroll
                for (int fm = 0; fm < 2; ++fm)
                    af[fm] = *(const bf16x8*)&as_[am + fm * 16][kk * 32 + coff];
                #pragma unroll
                for (int fn = 0; fn < 2; ++fn)
                    bf[fn] = *(const bf16x8*)&bs_[bn + fn * 16][kk * 32 + coff];
                #pragma unroll
                for (int fm = 0; fm < 2; ++fm)
                    #pragma unroll
                    for (int fn = 0; fn < 2; ++fn)
                        acc[fm][fn] = __builtin_amdgcn_mfma_f32_16x16x32_bf16(
                            af[fm], bf[fn], acc[fm][fn], 0, 0, 0);
            }
        }
        int mrow = it * 64 + wm * 32 + (lane >> 4) * 4;
        int ncol = h * kDH + wn * 32 + (lane & 15);
        #pragma unroll
        for (int fm = 0; fm < 2; ++fm)
            #pragma unroll
            for (int fn = 0; fn < 2; ++fn)
                #pragma unroll
                for (int rr = 0; rr < 4; ++rr)
                    out[((size_t)b * kL + mrow + fm * 16 + rr) * kD + ncol + fn * 16] =
                        acc[fm][fn][rr];
    } else {
        // ---------------- loss stage 1 branch ----------------
        int lb = blk - 512;
        if (lb < 6) {
            int idx = lb * 256 + tid;      // < 1536
            float s = 0.f;
            for (int bh = 0; bh < kBH; ++bh)
                s += spbuf[bh * (kL * 3) + idx];
            imps_buf[idx] = s;
        } else {
            int eb = lb - 6;               // 0..31
            const float* src = entbuf + eb * 1024 + tid * 4;
            float4 v4 = *(const float4*)src;
            float s = v4.x + v4.y + v4.z + v4.w;
            __shared__ float red[256];
            red[tid] = s;
            __syncthreads();
            for (int st = 128; st > 0; st >>= 1) {
                if (tid < st) red[tid] += red[tid + st];
                __syncthreads();
            }
            if (tid == 0) entpart[eb] = red[0];
        }
    }
}

// ---------------------------------------------------------------------------
// K7b: loss stage 2 (single block): mean/var of imps (ddof=1) + entropy total
// ---------------------------------------------------------------------------
__global__ __launch_bounds__(256) void k_loss2(const float* __restrict__ imps_buf,
        const float* __restrict__ entpart, float* __restrict__ out_loss) {
    __shared__ float red[256];
    int tid = threadIdx.x;
    float im[6];
    #pragma unroll
    for (int t = 0; t < 6; ++t) im[t] = imps_buf[t * 256 + tid];
    float ms = im[0] + im[1] + im[2] + im[3] + im[4] + im[5];
    red[tid] = ms;
    __syncthreads();
    for (int st = 128; st > 0; st >>= 1) {
        if (tid < st) red[tid] += red[tid + st];
        __syncthreads();
    }
    float mean = red[0] / (float)(kL * 3);
    __syncthreads();
    float vs = 0.f;
    #pragma unroll
    for (int t = 0; t < 6; ++t) { float d = im[t] - mean; vs = fmaf(d, d, vs); }
    red[tid] = vs;
    __syncthreads();
    for (int st = 128; st > 0; st >>= 1) {
        if (tid < st) red[tid] += red[tid + st];
        __syncthreads();
    }
    float var = red[0] / (float)(kL * 3 - 1);
    __syncthreads();
    red[tid] = (tid < 32) ? entpart[tid] : 0.f;
    __syncthreads();
    for (int st = 128; st > 0; st >>= 1) {
        if (tid < st) red[tid] += red[tid + st];
        __syncthreads();
    }
    if (tid == 0) {
        float loss_imp = var / (mean * mean + 1e-10f);
        float loss_dyn = -red[0] / (float)(kBH * 3);
        out_loss[0] = loss_imp + 0.1f * loss_dyn;
    }
}

// ---------------------------------------------------------------------------
extern "C" void kernel_launch(void* const* d_in, const int* in_sizes, int n_in,
                              void* d_out, int out_size, void* d_ws, size_t ws_size,
                              hipStream_t stream) {
    const float* x     = (const float*)d_in[0];
    const float* W1    = (const float*)d_in[2];
    const float* b1    = (const float*)d_in[3];
    const float* W2    = (const float*)d_in[4];
    const float* b2    = (const float*)d_in[5];
    const float* Wg    = (const float*)d_in[6];
    const float* Wp    = (const float*)d_in[7];
    const float* bp    = (const float*)d_in[8];
    float* out = (float*)d_out;
    float* ws  = (float*)d_ws;

    // workspace layout (float units). adjb overlays qh/ql/kh/kl (dead after
    // k_adj; stream order serializes k_adj -> k_select).
    float*  adj    = ws;                          // [0, 16777216)
    ushort* qh     = (ushort*)(ws + 16777216);
    ushort* ql     = (ushort*)(ws + 17825792);
    ushort* kh     = (ushort*)(ws + 18874368);
    ushort* kl     = (ushort*)(ws + 19922944);
    ushort* adjb   = (ushort*)(ws + 16777216);    // overlays qh..kl + extra
    ushort* xpbT   = (ushort*)(ws + 25165824);
    float*  spbuf  = ws + 26214400;               // 98,304
    float*  entbuf = ws + 26312704;               // 32,768
    float*  imps_b = ws + 26345472;               // 1,536
    float*  entprt = ws + 26347008;               // 32

    k_qk_xp<<<1024, 256, 0, stream>>>(x, W1, b1, W2, b2, Wp, bp,
                                      qh, ql, kh, kl, xpbT);
    k_adj<<<kBH * 64, 256, 0, stream>>>(qh, ql, kh, kl, adj);
    k_select<<<kROWS / 4, 256, 0, stream>>>(adj, Wg, adjb, spbuf, entbuf);
    k_out_loss1<<<550, 256, 0, stream>>>(adjb, xpbT, out, spbuf, entbuf,
                                         imps_b, entprt);
    k_loss2<<<1, 256, 0, stream>>>(imps_b, entprt, out + (size_t)kB * kL * kD);
}

// Round 18
// 100.107 us; speedup vs baseline: 1.0370x; 1.0183x over previous
//
#include <hip/hip_runtime.h>
#include <hip/hip_bf16.h>
#include <math.h>

// Problem constants
static constexpr int kB = 8;
static constexpr int kH = 8;
static constexpr int kL = 512;
static constexpr int kD = 512;
static constexpr int kDH = 64;     // D/H
static constexpr int kBH = 64;     // B*H
static constexpr int kROWS = kBH * kL;  // 32768

typedef short bf16x8 __attribute__((ext_vector_type(8)));
typedef float f32x4 __attribute__((ext_vector_type(4)));

// RNE float->bf16 (finite inputs only)
__device__ __forceinline__ ushort f2bf(float f) {
    unsigned u = __float_as_uint(f);
    unsigned r = u + 0x7fffu + ((u >> 16) & 1u);
    return (ushort)(r >> 16);
}
__device__ __forceinline__ float bf2f(ushort h) {
    return __uint_as_float((unsigned)h << 16);
}
// order-isomorphic float<->uint maps (finite, no NaN; -0.0 < +0.0 in key order)
__device__ __forceinline__ unsigned mapf(float f) {
    unsigned u = __float_as_uint(f);
    return (u & 0x80000000u) ? ~u : (u | 0x80000000u);
}
__device__ __forceinline__ float unmapf(unsigned u) {
    return (u & 0x80000000u) ? __uint_as_float(u ^ 0x80000000u)
                             : __uint_as_float(~u);
}

// ---------------------------------------------------------------------------
// DPP wave-64 reductions (VALU-only, ~6 ops; replaces ds_bpermute butterflies)
// row_shr 1/2/4/8 accumulate within 16-lane rows, row_bcast15 (rows 1,3),
// row_bcast31 (rows 2,3), then readlane 63 -> wave-uniform sgpr.
// ---------------------------------------------------------------------------
__device__ __forceinline__ float dpp_sum(float x) {
    x += __int_as_float(__builtin_amdgcn_update_dpp(0, __float_as_int(x), 0x111, 0xf, 0xf, true));
    x += __int_as_float(__builtin_amdgcn_update_dpp(0, __float_as_int(x), 0x112, 0xf, 0xf, true));
    x += __int_as_float(__builtin_amdgcn_update_dpp(0, __float_as_int(x), 0x114, 0xf, 0xf, true));
    x += __int_as_float(__builtin_amdgcn_update_dpp(0, __float_as_int(x), 0x118, 0xf, 0xf, true));
    x += __int_as_float(__builtin_amdgcn_update_dpp(0, __float_as_int(x), 0x142, 0xa, 0xf, true));
    x += __int_as_float(__builtin_amdgcn_update_dpp(0, __float_as_int(x), 0x143, 0xc, 0xf, true));
    return __int_as_float(__builtin_amdgcn_readlane(__float_as_int(x), 63));
}
__device__ __forceinline__ unsigned dpp_umax(unsigned x) {
    unsigned y;
    y = (unsigned)__builtin_amdgcn_update_dpp(0, (int)x, 0x111, 0xf, 0xf, true); x = x > y ? x : y;
    y = (unsigned)__builtin_amdgcn_update_dpp(0, (int)x, 0x112, 0xf, 0xf, true); x = x > y ? x : y;
    y = (unsigned)__builtin_amdgcn_update_dpp(0, (int)x, 0x114, 0xf, 0xf, true); x = x > y ? x : y;
    y = (unsigned)__builtin_amdgcn_update_dpp(0, (int)x, 0x118, 0xf, 0xf, true); x = x > y ? x : y;
    y = (unsigned)__builtin_amdgcn_update_dpp(0, (int)x, 0x142, 0xa, 0xf, true); x = x > y ? x : y;
    y = (unsigned)__builtin_amdgcn_update_dpp(0, (int)x, 0x143, 0xc, 0xf, true); x = x > y ? x : y;
    return (unsigned)__builtin_amdgcn_readlane((int)x, 63);
}
__device__ __forceinline__ unsigned dpp_umin(unsigned x) {
    return ~dpp_umax(~x);
}

// gelu with A&S 7.1.26 erf (max abs err ~1.5e-7, monotone-preserving)
__device__ __forceinline__ float gelu_fast(float v) {
    float z = v * 0.70710678118654752440f;
    float az = fabsf(z);
    float t = 1.0f / (1.0f + 0.3275911f * az);
    float ex = __expf(-az * az);
    float poly = t * (0.254829592f + t * (-0.284496736f + t * (1.421413741f +
                 t * (-1.453152027f + t * 1.061405429f))));
    float erfv = 1.0f - poly * ex;
    erfv = (z < 0.0f) ? -erfv : erfv;
    return 0.5f * v * (1.0f + erfv);
}

// ---------------------------------------------------------------------------
// K1 (merged): blocks 0..511: q/k projection (split-bf16 MFMA, hi/lo out);
// blocks 512..1023: xp = x @ Wp^T + bp -> transposed bf16 xpbT (MFMA).
// ---------------------------------------------------------------------------
__global__ __launch_bounds__(256) void k_qk_xp(const float* __restrict__ x,
        const float* __restrict__ W1, const float* __restrict__ b1,
        const float* __restrict__ W2, const float* __restrict__ b2,
        const float* __restrict__ Wp, const float* __restrict__ bp,
        ushort* __restrict__ qh, ushort* __restrict__ ql,
        ushort* __restrict__ kh, ushort* __restrict__ kl,
        ushort* __restrict__ xpbT) {
    __shared__ __align__(16) char smem[2 * 64 * 72 * 2];
    int tid = threadIdx.x;
    int blk = blockIdx.x;
    int lane = tid & 63, wave = tid >> 6;
    if (blk < 512) {
        // ------- qk branch (split-bf16 MFMA; q||k, 4 waves: wq x wn) -------
        int b = blk >> 6, h = (blk >> 3) & 7, lt = blk & 7;
        ushort (*xhi)[72] = (ushort(*)[72])smem;
        ushort (*xlo)[72] = (ushort(*)[72])(smem + 64 * 72 * 2);
        {
            int r = tid >> 2, s = tid & 3;
            const float* src = x + (size_t)(b * kL + lt * 64 + r) * kD + h * kDH + s * 16;
            union { ushort u[16]; int4 v[2]; } ph, pl;
            #pragma unroll
            for (int c4 = 0; c4 < 4; ++c4) {
                float4 f = *(const float4*)(src + c4 * 4);
                float fv[4] = {f.x, f.y, f.z, f.w};
                #pragma unroll
                for (int t = 0; t < 4; ++t) {
                    ushort hh = f2bf(fv[t]);
                    ph.u[c4 * 4 + t] = hh;
                    pl.u[c4 * 4 + t] = f2bf(fv[t] - bf2f(hh));
                }
            }
            *(int4*)&xhi[r][s * 16] = ph.v[0];
            *(int4*)&xhi[r][s * 16 + 8] = ph.v[1];
            *(int4*)&xlo[r][s * 16] = pl.v[0];
            *(int4*)&xlo[r][s * 16 + 8] = pl.v[1];
        }
        int wq = wave >> 1, wn = wave & 1;
        const float* Wm = wq ? W2 : W1;
        const float* bias = wq ? b2 : b1;
        int coff = (lane >> 4) * 8;
        bf16x8 bh8[2][2], bl8[2][2];   // [fn][kk]
        #pragma unroll
        for (int fn = 0; fn < 2; ++fn) {
            int browg = wn * 32 + fn * 16 + (lane & 15);
            #pragma unroll
            for (int kk = 0; kk < 2; ++kk) {
                const float* wsrc = Wm + browg * 64 + kk * 32 + coff;
                float4 f0 = *(const float4*)(wsrc);
                float4 f1 = *(const float4*)(wsrc + 4);
                float fv[8] = {f0.x, f0.y, f0.z, f0.w, f1.x, f1.y, f1.z, f1.w};
                union { ushort u[8]; bf16x8 v; } uh, ul;
                #pragma unroll
                for (int t = 0; t < 8; ++t) {
                    ushort hh = f2bf(fv[t]);
                    uh.u[t] = hh;
                    ul.u[t] = f2bf(fv[t] - bf2f(hh));
                }
                bh8[fn][kk] = uh.v;
                bl8[fn][kk] = ul.v;
            }
        }
        __syncthreads();
        f32x4 acc[4][2] = {};
        #pragma unroll
        for (int kk = 0; kk < 2; ++kk)
            #pragma unroll
            for (int fm = 0; fm < 4; ++fm) {
                bf16x8 ah8 = *(const bf16x8*)&xhi[fm * 16 + (lane & 15)][kk * 32 + coff];
                bf16x8 al8 = *(const bf16x8*)&xlo[fm * 16 + (lane & 15)][kk * 32 + coff];
                #pragma unroll
                for (int fn = 0; fn < 2; ++fn) {
                    acc[fm][fn] = __builtin_amdgcn_mfma_f32_16x16x32_bf16(
                        ah8, bh8[fn][kk], acc[fm][fn], 0, 0, 0);
                    acc[fm][fn] = __builtin_amdgcn_mfma_f32_16x16x32_bf16(
                        ah8, bl8[fn][kk], acc[fm][fn], 0, 0, 0);
                    acc[fm][fn] = __builtin_amdgcn_mfma_f32_16x16x32_bf16(
                        al8, bh8[fn][kk], acc[fm][fn], 0, 0, 0);
                }
            }
        ushort* dh = wq ? kh : qh;
        ushort* dl = wq ? kl : ql;
        #pragma unroll
        for (int fm = 0; fm < 4; ++fm)
            #pragma unroll
            for (int fn = 0; fn < 2; ++fn) {
                int col = wn * 32 + fn * 16 + (lane & 15);
                float bv = bias[col];
                #pragma unroll
                for (int rr = 0; rr < 4; ++rr) {
                    int row = lt * 64 + fm * 16 + (lane >> 4) * 4 + rr;
                    int o = ((b * kH + h) * kL + row) * kDH + col;
                    float val = acc[fm][fn][rr] + bv;
                    ushort hh = f2bf(val);
                    dh[o] = hh;
                    dl[o] = f2bf(val - bf2f(hh));
                }
            }
    } else {
        // ---------------- xp branch (MFMA bf16, transposed store) ----------
        int bxp = blk - 512;
        int it = bxp >> 3, jt = bxp & 7;
        ushort (*xbs)[72] = (ushort(*)[72])smem;
        ushort (*wbs)[72] = (ushort(*)[72])(smem + 64 * 72 * 2);
        int r = tid >> 2, s = tid & 3;
        int wm = wave >> 1, wn = wave & 1;
        int am = wm * 32 + (lane & 15);
        int bn = wn * 32 + (lane & 15);
        int coff = (lane >> 4) * 8;
        f32x4 acc[2][2] = {};
        const float* xsrc = x + (size_t)(it * 64 + r) * kD + s * 16;
        const float* wsrc = Wp + (size_t)(jt * 64 + r) * kD + s * 16;
        for (int kt = 0; kt < 8; ++kt) {
            union { ushort u[16]; int4 v[2]; } px, pw;
            #pragma unroll
            for (int c4 = 0; c4 < 4; ++c4) {
                float4 fx = *(const float4*)(xsrc + kt * 64 + c4 * 4);
                float4 fw = *(const float4*)(wsrc + kt * 64 + c4 * 4);
                px.u[c4 * 4 + 0] = f2bf(fx.x); px.u[c4 * 4 + 1] = f2bf(fx.y);
                px.u[c4 * 4 + 2] = f2bf(fx.z); px.u[c4 * 4 + 3] = f2bf(fx.w);
                pw.u[c4 * 4 + 0] = f2bf(fw.x); pw.u[c4 * 4 + 1] = f2bf(fw.y);
                pw.u[c4 * 4 + 2] = f2bf(fw.z); pw.u[c4 * 4 + 3] = f2bf(fw.w);
            }
            __syncthreads();
            *(int4*)&xbs[r][s * 16] = px.v[0];
            *(int4*)&xbs[r][s * 16 + 8] = px.v[1];
            *(int4*)&wbs[r][s * 16] = pw.v[0];
            *(int4*)&wbs[r][s * 16 + 8] = pw.v[1];
            __syncthreads();
            #pragma unroll
            for (int kk = 0; kk < 2; ++kk) {
                bf16x8 af[2], bf[2];
                #pragma unroll
                for (int fm = 0; fm < 2; ++fm)
                    af[fm] = *(const bf16x8*)&xbs[am + fm * 16][kk * 32 + coff];
                #pragma unroll
                for (int fn = 0; fn < 2; ++fn)
                    bf[fn] = *(const bf16x8*)&wbs[bn + fn * 16][kk * 32 + coff];
                #pragma unroll
                for (int fm = 0; fm < 2; ++fm)
                    #pragma unroll
                    for (int fn = 0; fn < 2; ++fn)
                        acc[fm][fn] = __builtin_amdgcn_mfma_f32_16x16x32_bf16(
                            af[fm], bf[fn], acc[fm][fn], 0, 0, 0);
            }
        }
        #pragma unroll
        for (int fn = 0; fn < 2; ++fn) {
            int dcol = jt * 64 + wn * 32 + (lane & 15) + fn * 16;
            float bpv = bp[dcol];
            #pragma unroll
            for (int fm = 0; fm < 2; ++fm) {
                int l0 = it * 64 + wm * 32 + fm * 16 + (lane >> 4) * 4;
                union { ushort u[4]; uint2 v; } pk;
                #pragma unroll
                for (int rr = 0; rr < 4; ++rr)
                    pk.u[rr] = f2bf(acc[fm][fn][rr] + bpv);
                *(uint2*)&xpbT[(size_t)dcol * (size_t)(kB * kL) + l0] = pk.v;
            }
        }
    }
}

// ---------------------------------------------------------------------------
// K2 (MFMA, split-bf16): adj = gelu(q @ k^T) per (b,h). 64x64 tile, K=64.
// ---------------------------------------------------------------------------
__global__ __launch_bounds__(256) void k_adj(const ushort* __restrict__ qh,
        const ushort* __restrict__ ql, const ushort* __restrict__ kh,
        const ushort* __restrict__ kl, float* __restrict__ adj) {
    int blk = blockIdx.x;
    int bh = blk >> 6;
    int it = (blk >> 3) & 7, jt = blk & 7;
    __shared__ ushort ah[64][72], al[64][72];
    __shared__ ushort bh_[64][72], bl[64][72];
    int tid = threadIdx.x;
    int r = tid >> 2, s = tid & 3;
    size_t aoff = (size_t)(bh * kL + it * 64 + r) * kDH + s * 16;
    size_t boff = (size_t)(bh * kL + jt * 64 + r) * kDH + s * 16;
    *(int4*)&ah[r][s * 16]  = *(const int4*)&qh[aoff];
    *(int4*)&ah[r][s * 16 + 8]  = *(const int4*)&qh[aoff + 8];
    *(int4*)&al[r][s * 16]  = *(const int4*)&ql[aoff];
    *(int4*)&al[r][s * 16 + 8]  = *(const int4*)&ql[aoff + 8];
    *(int4*)&bh_[r][s * 16] = *(const int4*)&kh[boff];
    *(int4*)&bh_[r][s * 16 + 8] = *(const int4*)&kh[boff + 8];
    *(int4*)&bl[r][s * 16]  = *(const int4*)&kl[boff];
    *(int4*)&bl[r][s * 16 + 8]  = *(const int4*)&kl[boff + 8];
    __syncthreads();
    int lane = tid & 63, wave = tid >> 6;
    int wm = wave >> 1, wn = wave & 1;
    int am = wm * 32 + (lane & 15);
    int bn = wn * 32 + (lane & 15);
    int coff = (lane >> 4) * 8;
    f32x4 acc[2][2] = {};
    #pragma unroll
    for (int kk = 0; kk < 2; ++kk) {
        bf16x8 afh[2], afl[2], bfh[2], bfl[2];
        #pragma unroll
        for (int fm = 0; fm < 2; ++fm) {
            afh[fm] = *(const bf16x8*)&ah[am + fm * 16][kk * 32 + coff];
            afl[fm] = *(const bf16x8*)&al[am + fm * 16][kk * 32 + coff];
        }
        #pragma unroll
        for (int fn = 0; fn < 2; ++fn) {
            bfh[fn] = *(const bf16x8*)&bh_[bn + fn * 16][kk * 32 + coff];
            bfl[fn] = *(const bf16x8*)&bl[bn + fn * 16][kk * 32 + coff];
        }
        #pragma unroll
        for (int fm = 0; fm < 2; ++fm)
            #pragma unroll
            for (int fn = 0; fn < 2; ++fn) {
                acc[fm][fn] = __builtin_amdgcn_mfma_f32_16x16x32_bf16(
                    afh[fm], bfh[fn], acc[fm][fn], 0, 0, 0);
                acc[fm][fn] = __builtin_amdgcn_mfma_f32_16x16x32_bf16(
                    afh[fm], bfl[fn], acc[fm][fn], 0, 0, 0);
                acc[fm][fn] = __builtin_amdgcn_mfma_f32_16x16x32_bf16(
                    afl[fm], bfh[fn], acc[fm][fn], 0, 0, 0);
            }
    }
    int mrow = it * 64 + wm * 32 + (lane >> 4) * 4;
    int ncol = jt * 64 + wn * 32 + (lane & 15);
    #pragma unroll
    for (int fm = 0; fm < 2; ++fm)
        #pragma unroll
        for (int fn = 0; fn < 2; ++fn)
            #pragma unroll
            for (int rr = 0; rr < 4; ++rr)
                adj[((size_t)bh * kL + mrow + fm * 16 + rr) * kL + ncol + fn * 16] =
                    gelu_fast(acc[fm][fn][rr]);
}

// ---------------------------------------------------------------------------
// K3 (fused): per-row, one wave. Exact 256th-smallest via RADIX-4 ballot
// bisection (integer key space, -0.0 safe), boundary early-exits, integer
// extraction (DPP reductions). Then threshold, logits, softmax-3, top-p,
// computed masks, row softmax (no max-subtract), bf16 adjb write.
// All cross-lane reductions use DPP (VALU) instead of ds_bpermute shuffles.
// grid = ROWS/4.
// ---------------------------------------------------------------------------
__global__ __launch_bounds__(256) void k_select(const float* __restrict__ adj,
        const float* __restrict__ Wg,
        ushort* __restrict__ adjb,
        float* __restrict__ spbuf, float* __restrict__ entbuf) {
    int tid = threadIdx.x;
    int wave = tid >> 6, lane = tid & 63;
    int row = blockIdx.x * 4 + wave;
    int i = row & (kL - 1);
    const float* arow = adj + (size_t)row * kL;
    int j0 = lane * 8;

    float v[8];
    {
        float4 a0 = *(const float4*)&arow[j0];
        float4 a1 = *(const float4*)&arow[j0 + 4];
        v[0] = a0.x; v[1] = a0.y; v[2] = a0.z; v[3] = a0.w;
        v[4] = a1.x; v[5] = a1.y; v[6] = a1.z; v[7] = a1.w;
    }
    unsigned key[8];
    #pragma unroll
    for (int t = 0; t < 8; ++t) key[t] = mapf(v[t]);

    // radix-4 bisection, k = 255 (0-indexed), integer key space
    unsigned prefix = 0;
    int cbp = 0, cin = 512;
    int bit = 31;
    int mode = 0;                   // 0: exhausted, 1: extract-min, 2: extract-max
    while (bit >= 1) {
        unsigned qsz = 1u << (bit - 1);
        unsigned q1 = prefix + qsz;
        unsigned q2 = prefix + 2u * qsz;
        unsigned q3 = prefix + 3u * qsz;
        int c1 = 0, c2 = 0, c3 = 0;
        #pragma unroll
        for (int t = 0; t < 8; ++t) {
            c1 += (int)__popcll(__ballot(key[t] < q1));
            c2 += (int)__popcll(__ballot(key[t] < q2));
            c3 += (int)__popcll(__ballot(key[t] < q3));
        }
        if (255 < c1)      { cin = c1 - cbp; }
        else if (255 < c2) { cin = c2 - c1;  prefix = q1; cbp = c1; }
        else if (255 < c3) { cin = c3 - c2;  prefix = q2; cbp = c2; }
        else               { cin = cin - (c3 - cbp); prefix = q3; cbp = c3; }
        bit -= 2;
        int loc = 255 - cbp;        // local rank of kth within interval
        if (cin == 1)        { mode = 2; break; }
        if (loc == 0)        { mode = 1; break; }
        if (loc == cin - 1)  { mode = 2; break; }
    }
    float thr;
    if (mode == 0) {
        thr = unmapf(prefix);       // all bits resolved: exact key
    } else {
        unsigned width = 1u << (bit + 1);   // bit in [-1,29]
        unsigned acc = (mode == 1) ? 0xFFFFFFFFu : 0u;
        #pragma unroll
        for (int t = 0; t < 8; ++t) {
            unsigned d = key[t] - prefix;
            bool mem = d < width;
            if (mode == 1) acc = (mem && key[t] < acc) ? key[t] : acc;
            else           acc = (mem && key[t] > acc) ? key[t] : acc;
        }
        acc = (mode == 1) ? dpp_umin(acc) : dpp_umax(acc);
        thr = unmapf(acc);
    }

    // threshold + logits (Wg as float4)
    union { float4 f4[2]; float f[8]; } wg0, wg1, wg2;
    wg0.f4[0] = *(const float4*)&Wg[j0];          wg0.f4[1] = *(const float4*)&Wg[j0 + 4];
    wg1.f4[0] = *(const float4*)&Wg[kL + j0];     wg1.f4[1] = *(const float4*)&Wg[kL + j0 + 4];
    wg2.f4[0] = *(const float4*)&Wg[2 * kL + j0]; wg2.f4[1] = *(const float4*)&Wg[2 * kL + j0 + 4];
    float l0 = 0.f, l1 = 0.f, l2 = 0.f;
    #pragma unroll
    for (int t = 0; t < 8; ++t) {
        float nv = (v[t] > thr) ? v[t] : 0.0f;
        v[t] = nv;
        l0 = fmaf(nv, wg0.f[t], l0);
        l1 = fmaf(nv, wg1.f[t], l1);
        l2 = fmaf(nv, wg2.f[t], l2);
    }
    l0 = dpp_sum(l0);
    l1 = dpp_sum(l1);
    l2 = dpp_sum(l2);
    // softmax-3 + stable top-p (all lanes redundantly; wave-uniform)
    float m = fmaxf(l0, fmaxf(l1, l2));
    float e0 = __expf(l0 - m), e1 = __expf(l1 - m), e2 = __expf(l2 - m);
    float s = e0 + e1 + e2;
    float p[3] = {e0 / s, e1 / s, e2 / s};
    int o0, o1, o2;
    if (p[0] >= p[1] && p[0] >= p[2]) o0 = 0;
    else if (p[1] >= p[2]) o0 = 1;
    else o0 = 2;
    int r0 = (o0 == 0) ? 1 : 0;
    int r1 = (o0 == 2) ? 1 : 2;
    if (p[r0] >= p[r1]) { o1 = r0; o2 = r1; } else { o1 = r1; o2 = r0; }
    float sp0 = p[o0], sp1 = p[o1], sp2 = p[o2];
    float c0 = sp0, c1 = sp0 + sp1, c2 = c1 + sp2;
    bool m0 = c0 > 0.5f, m1 = c1 > 0.5f, m2 = c2 > 0.5f;
    int ti = m0 ? 0 : (m1 ? 1 : 2);
    bool mm0 = m0 && (ti != 0);
    bool mm1 = m1 && (ti != 1);
    bool mm2 = m2 && (ti != 2);
    float g[3] = {0.f, 0.f, 0.f};
    g[o0] = mm0 ? 0.f : 1.f;
    g[o1] = mm1 ? 0.f : 1.f;
    g[o2] = mm2 ? 0.f : 1.f;
    if (lane == 0) {
        spbuf[row * 3 + 0] = mm0 ? 0.f : sp0;
        spbuf[row * 3 + 1] = mm1 ? 0.f : sp1;
        spbuf[row * 3 + 2] = mm2 ? 0.f : sp2;
        entbuf[row] = p[0] * __logf(p[0] + 1e-10f) +
                      p[1] * __logf(p[1] + 1e-10f) +
                      p[2] * __logf(p[2] + 1e-10f);
    }

    // computed masks: S (same mod-64 residue, j!=i) -> g0; T (same 64-block,
    // incl diag) -> g1 (+1 on diag); else -> g2
    int i6 = i >> 6, i63 = i & 63;
    bool inb = ((lane >> 3) == i6);             // lane's 8 elems share j>>6
    float sel1 = inb ? (g[1] + 1.0f) : g[0];
    float sel0 = inb ? g[1] : g[2];
    int lane8 = (lane & 7) * 8;
    // row softmax without max-subtract (|av| <= ~30 -> exp safe in fp32)
    float e[8], ls = 0.f;
    #pragma unroll
    for (int t = 0; t < 8; ++t) {
        bool ing = (lane8 + t) == i63;
        float av = v[t] * (ing ? sel1 : sel0);
        e[t] = __expf(av);
        ls += e[t];
    }
    ls = dpp_sum(ls);
    float inv = 1.0f / ls;
    union { ushort u[8]; int4 vv; } pk;
    #pragma unroll
    for (int t = 0; t < 8; ++t) pk.u[t] = f2bf(e[t] * inv);
    *(int4*)&adjb[(size_t)row * kL + j0] = pk.vv;
}

// ---------------------------------------------------------------------------
// K6 (merged): blocks 0..511: out = adjb @ xpbT (MFMA);
// blocks 512..549: loss stage 1 (imps col-sums + entropy partials).
// ---------------------------------------------------------------------------
__global__ __launch_bounds__(256) void k_out_loss1(const ushort* __restrict__ adjb,
        const ushort* __restrict__ xpbT, float* __restrict__ out,
        const float* __restrict__ spbuf, const float* __restrict__ entbuf,
        float* __restrict__ imps_buf, float* __restrict__ entpart) {
    int tid = threadIdx.x;
    int blk = blockIdx.x;
    if (blk < 512) {
        // ---------------- out branch ----------------
        __shared__ ushort as_[64][72];
        __shared__ ushort bs_[64][72];
        int bh = blk >> 3, it = blk & 7;
        int b = bh >> 3, h = bh & 7;
        int lane = tid & 63, wave = tid >> 6;
        int wm = wave >> 1, wn = wave & 1;
        int r = tid >> 2, s = tid & 3;
        const ushort* aG = adjb + ((size_t)(bh * kL + it * 64 + r)) * kL + s * 16;
        const ushort* bG = xpbT + ((size_t)(h * kDH + r)) * (size_t)(kB * kL) + b * kL + s * 16;
        f32x4 acc[2][2] = {};
        int am = wm * 32 + (lane & 15);
        int bn = wn * 32 + (lane & 15);
        int coff = (lane >> 4) * 8;
        for (int kt = 0; kt < 8; ++kt) {
            int4 a0 = *(const int4*)(aG + kt * 64);
            int4 a1 = *(const int4*)(aG + kt * 64 + 8);
            int4 b0 = *(const int4*)(bG + kt * 64);
            int4 b1 = *(const int4*)(bG + kt * 64 + 8);
            __syncthreads();
            *(int4*)&as_[r][s * 16] = a0;
            *(int4*)&as_[r][s * 16 + 8] = a1;
            *(int4*)&bs_[r][s * 16] = b0;
            *(int4*)&bs_[r][s * 16 + 8] = b1;
            __syncthreads();
            #pragma unroll
            for (int kk = 0; kk < 2; ++kk) {
                bf16x8 af[2], bf[2];
                #pragma unroll
                for (int fm = 0; fm < 2; ++fm)
                    af[fm] = *(const bf16x8*)&as_[am + fm * 16][kk * 32 + coff];
                #pragma unroll
                for (int fn = 0; fn < 2; ++fn)
                    bf[fn] = *(const bf16x8*)&bs_[bn + fn * 16][kk * 32 + coff];
                #pragma unroll
                for (int fm = 0; fm < 2; ++fm)
                    #pragma unroll
                    for (int fn = 0; fn < 2; ++fn)
                        acc[fm][fn] = __builtin_amdgcn_mfma_f32_16x16x32_bf16(
                            af[fm], bf[fn], acc[fm][fn], 0, 0, 0);
            }
        }
        int mrow = it * 64 + wm * 32 + (lane >> 4) * 4;
        int ncol = h * kDH + wn * 32 + (lane & 15);
        #pragma unroll
        for (int fm = 0; fm < 2; ++fm)
            #pragma unroll
            for (int fn = 0; fn < 2; ++fn)
                #pragma unroll
                for (int rr = 0; rr < 4; ++rr)
                    out[((size_t)b * kL + mrow + fm * 16 + rr) * kD + ncol + fn * 16] =
                        acc[fm][fn][rr];
    } else {
        // ---------------- loss stage 1 branch ----------------
        int lb = blk - 512;
        if (lb < 6) {
            int idx = lb * 256 + tid;      // < 1536
            float s = 0.f;
            for (int bh = 0; bh < kBH; ++bh)
                s += spbuf[bh * (kL * 3) + idx];
            imps_buf[idx] = s;
        } else {
            int eb = lb - 6;               // 0..31
            const float* src = entbuf + eb * 1024 + tid * 4;
            float4 v4 = *(const float4*)src;
            float s = v4.x + v4.y + v4.z + v4.w;
            __shared__ float red[256];
            red[tid] = s;
            __syncthreads();
            for (int st = 128; st > 0; st >>= 1) {
                if (tid < st) red[tid] += red[tid + st];
                __syncthreads();
            }
            if (tid == 0) entpart[eb] = red[0];
        }
    }
}

// ---------------------------------------------------------------------------
// K7b: loss stage 2 (single block): mean/var of imps (ddof=1) + entropy total
// ---------------------------------------------------------------------------
__global__ __launch_bounds__(256) void k_loss2(const float* __restrict__ imps_buf,
        const float* __restrict__ entpart, float* __restrict__ out_loss) {
    __shared__ float red[256];
    int tid = threadIdx.x;
    float im[6];
    #pragma unroll
    for (int t = 0; t < 6; ++t) im[t] = imps_buf[t * 256 + tid];
    float ms = im[0] + im[1] + im[2] + im[3] + im[4] + im[5];
    red[tid] = ms;
    __syncthreads();
    for (int st = 128; st > 0; st >>= 1) {
        if (tid < st) red[tid] += red[tid + st];
        __syncthreads();
    }
    float mean = red[0] / (float)(kL * 3);
    __syncthreads();
    float vs = 0.f;
    #pragma unroll
    for (int t = 0; t < 6; ++t) { float d = im[t] - mean; vs = fmaf(d, d, vs); }
    red[tid] = vs;
    __syncthreads();
    for (int st = 128; st > 0; st >>= 1) {
        if (tid < st) red[tid] += red[tid + st];
        __syncthreads();
    }
    float var = red[0] / (float)(kL * 3 - 1);
    __syncthreads();
    red[tid] = (tid < 32) ? entpart[tid] : 0.f;
    __syncthreads();
    for (int st = 128; st > 0; st >>= 1) {
        if (tid < st) red[tid] += red[tid + st];
        __syncthreads();
    }
    if (tid == 0) {
        float loss_imp = var / (mean * mean + 1e-10f);
        float loss_dyn = -red[0] / (float)(kBH * 3);
        out_loss[0] = loss_imp + 0.1f * loss_dyn;
    }
}

// ---------------------------------------------------------------------------
extern "C" void kernel_launch(void* const* d_in, const int* in_sizes, int n_in,
                              void* d_out, int out_size, void* d_ws, size_t ws_size,
                              hipStream_t stream) {
    const float* x     = (const float*)d_in[0];
    const float* W1    = (const float*)d_in[2];
    const float* b1    = (const float*)d_in[3];
    const float* W2    = (const float*)d_in[4];
    const float* b2    = (const float*)d_in[5];
    const float* Wg    = (const float*)d_in[6];
    const float* Wp    = (const float*)d_in[7];
    const float* bp    = (const float*)d_in[8];
    float* out = (float*)d_out;
    float* ws  = (float*)d_ws;

    // workspace layout (float units). adjb overlays qh/ql/kh/kl (dead after
    // k_adj; stream order serializes k_adj -> k_select).
    float*  adj    = ws;                          // [0, 16777216)
    ushort* qh     = (ushort*)(ws + 16777216);
    ushort* ql     = (ushort*)(ws + 17825792);
    ushort* kh     = (ushort*)(ws + 18874368);
    ushort* kl     = (ushort*)(ws + 19922944);
    ushort* adjb   = (ushort*)(ws + 16777216);    // overlays qh..kl + extra
    ushort* xpbT   = (ushort*)(ws + 25165824);
    float*  spbuf  = ws + 26214400;               // 98,304
    float*  entbuf = ws + 26312704;               // 32,768
    float*  imps_b = ws + 26345472;               // 1,536
    float*  entprt = ws + 26347008;               // 32

    k_qk_xp<<<1024, 256, 0, stream>>>(x, W1, b1, W2, b2, Wp, bp,
                                      qh, ql, kh, kl, xpbT);
    k_adj<<<kBH * 64, 256, 0, stream>>>(qh, ql, kh, kl, adj);
    k_select<<<kROWS / 4, 256, 0, stream>>>(adj, Wg, adjb, spbuf, entbuf);
    k_out_loss1<<<550, 256, 0, stream>>>(adjb, xpbT, out, spbuf, entbuf,
                                         imps_b, entprt);
    k_loss2<<<1, 256, 0, stream>>>(imps_b, entprt, out + (size_t)kB * kL * kD);
}